// Round 3
// baseline (69.215 us; speedup 1.0000x reference)
//
#include <hip/hip_runtime.h>

// KAN 2x2 convolution, stride 1, summed over C=16 input channels.
// x: (8,16,128,128) fp32 -> out: (8,1,127,127) fp32
//
// Round-5 structure (from round-4's 68.5 us):
//  - PACKED FP32 MATH: the 4-feature Horner at shared u is pairable;
//    v_pk_fma_f32 (VOP3P, 2 FMA/inst) does it in 6 pk-FMA + 2 pk-ADD
//    (was 12 FMA + 4 ADD), and the base-weight epilogue in 2 pk-FMA
//    (was 4). ~27% VALU cut per eval. Coef table repacked as
//    feature-pair quadrants so the same 4x ds_read_b128 feed the
//    packed ops directly.
//  - sfeat stored as float2 pairs: 2x ds_write_b64 (was 4x b32);
//    gather reads b64, 2-way bank aliasing = free.
//  - otherwise round-4 structure: 640 thr (2 channel-groups of 8),
//    512 blocks, zero coef row for out-of-grid, address-only OOB clamp,
//    single dispatch, no atomics, no memset, 2 barriers.

typedef __attribute__((ext_vector_type(2))) float f32x2;
typedef __attribute__((ext_vector_type(4))) float f32x4;

#define IN_F 4
#define N_COEF 8
#define N_INT 11      // valid knot intervals; row 11 of cpk is zeros
#define TW 32         // output tile width
#define TH 8          // output tile height
#define LW 33         // input tile width  (TW+1)
#define LH 9          // input tile height (TH+1)
#define NV (LW * LH)  // 297 input positions per tile
#define CPG 8         // channels per group
#define GT 320        // threads per group (5 waves; 297 active)
#define NT (2 * GT)   // 640 threads, 10 waves

#define LOV(v) __builtin_shufflevector(v, v, 0, 1)
#define HIV(v) __builtin_shufflevector(v, v, 2, 3)

__device__ __forceinline__ float silu_f(float x) {
    return x * __builtin_amdgcn_rcpf(1.0f + __expf(-x));
}

__device__ __forceinline__ f32x2 pk_fma(f32x2 a, f32x2 b, f32x2 c) {
    f32x2 d;
    asm("v_pk_fma_f32 %0, %1, %2, %3" : "=v"(d) : "v"(a), "v"(b), "v"(c));
    return d;
}
__device__ __forceinline__ f32x2 pk_add(f32x2 a, f32x2 b) {
    f32x2 d;
    asm("v_pk_add_f32 %0, %1, %2" : "=v"(d) : "v"(a), "v"(b));
    return d;
}

__global__ __launch_bounds__(NT) void kan_conv_kernel(
    const float* __restrict__ x,
    const float* __restrict__ base_w,    // (1,4)
    const float* __restrict__ spline_w,  // (1,4,8)
    const float* __restrict__ spline_s,  // (1,4)
    const float* __restrict__ grid,      // (4,12) identical uniform rows
    float* __restrict__ out,
    int B, int C, int H, int W)
{
    const int Ho = H - 1, Wo = W - 1;

    // cpk[t][0]=(c0f0,c0f1,c1f0,c1f1) cpk[t][1]=(c2f0,c2f1,c3f0,c3f1)
    // cpk[t][2]=(c0f2,c0f3,c1f2,c1f3) cpk[t][3]=(c2f2,c2f3,c3f2,c3f3)
    __shared__ f32x4 cpk[N_INT + 1][5];        // stride-5 float4 rows
    __shared__ f32x2 sfeat[2][2][NV + 7];      // [grp][pair01/pair23][pos]
    __shared__ float s_misc[6];                // bw0..3, g0, invh

    const int tid = threadIdx.x;

    // ---- one-time table build (tid 0..47): fold spline weights into
    //      per-(interval, feature-pair) power-basis cubics; t==11 -> zeros
    if (tid < (N_INT + 1) * IN_F) {
        const int t  = tid >> 2;
        const int q  = tid & 3;          // column in cpk
        const int pa = (q >> 1) * 2;     // feature pair base: 0 or 2
        const int kb = (q & 1) * 2;      // power pair base:   0 or 2
        const float M[4][4] = {
            {1.f/6.f, -3.f/6.f,  3.f/6.f, -1.f/6.f},
            {4.f/6.f,  0.f,     -6.f/6.f,  3.f/6.f},
            {1.f/6.f,  3.f/6.f,  3.f/6.f, -3.f/6.f},
            {0.f,      0.f,      0.f,      1.f/6.f}};
        float cc[4][2] = {{0.f,0.f},{0.f,0.f},{0.f,0.f},{0.f,0.f}};
        #pragma unroll
        for (int pp = 0; pp < 2; ++pp) {
            const int p = pa + pp;
            const float scal = spline_s[p];
            #pragma unroll
            for (int m = 0; m < 4; ++m) {
                const int j = t - 3 + m;
                const float w = (j >= 0 && j < N_COEF)
                                  ? spline_w[p * N_COEF + j] * scal : 0.f;
                #pragma unroll
                for (int k = 0; k < 4; ++k) cc[k][pp] += M[m][k] * w;
            }
        }
        f32x4 v;
        v.x = cc[kb][0];     v.y = cc[kb][1];
        v.z = cc[kb + 1][0]; v.w = cc[kb + 1][1];
        cpk[t][q] = v;
    }
    if (tid < IN_F) s_misc[tid] = base_w[tid];
    if (tid == 4)   s_misc[4] = grid[0];
    if (tid == 5)   s_misc[5] = 1.0f / (grid[1] - grid[0]);

    // ---- block decomposition: 4 xtiles x 16 ytiles x 8 batches = 512 ----
    int bid = blockIdx.x;
    const int txi = bid & 3;  bid >>= 2;
    const int tyi = bid & 15; bid >>= 4;
    const int b   = bid;
    const int tx0 = txi * TW, ty0 = tyi * TH;

    const int grp = (tid >= GT) ? 1 : 0;
    const int lt  = tid - grp * GT;      // 0..319 within group

    __syncthreads();

    const float g0 = s_misc[4], invh = s_misc[5];

    // ---- phase A: one input position per thread, 8 channels per group ----
    if (lt < NV) {
        const int r  = lt / LW;
        const int cc = lt - r * LW;
        const int iy = ty0 + r, ix = tx0 + cc;
        // OOB positions feed only masked-out outputs: clamp ADDRESS only.
        const bool inb = (iy < H) & (ix < W);
        const size_t cs = (size_t)H * W;
        const float* __restrict__ px =
            x + ((size_t)b * C + grp * CPG) * cs + (inb ? (iy * W + ix) : 0);

        float vals[CPG];
        #pragma unroll
        for (int c = 0; c < CPG; ++c) vals[c] = px[c * cs];

        f32x2 a01 = {0.f, 0.f}, a23 = {0.f, 0.f};
        float ssum = 0.f;
        #pragma unroll
        for (int c = 0; c < CPG; ++c) {
            const float val = vals[c];
            ssum += silu_f(val);
            const float tf  = (val - g0) * invh;
            const float tfl = floorf(tf);
            const int   ti  = (int)tfl;
            const float u   = tf - tfl;
            // out-of-grid -> zero row 11 (spline contribution exactly 0)
            const int   tc  = ((unsigned)ti < (unsigned)N_INT) ? ti : N_INT;
            const f32x4 q0 = cpk[tc][0];
            const f32x4 q1 = cpk[tc][1];
            const f32x4 q2 = cpk[tc][2];
            const f32x4 q3 = cpk[tc][3];
            f32x2 u2; u2.x = u; u2.y = u;
            f32x2 s01 = pk_fma(u2, HIV(q1), LOV(q1));  // u*c3 + c2
            s01 = pk_fma(u2, s01, HIV(q0));            // *u + c1
            s01 = pk_fma(u2, s01, LOV(q0));            // *u + c0
            a01 = pk_add(a01, s01);
            f32x2 s23 = pk_fma(u2, HIV(q3), LOV(q3));
            s23 = pk_fma(u2, s23, HIV(q2));
            s23 = pk_fma(u2, s23, LOV(q2));
            a23 = pk_add(a23, s23);
        }
        f32x2 ssum2; ssum2.x = ssum; ssum2.y = ssum;
        f32x2 bw01;  bw01.x = s_misc[0]; bw01.y = s_misc[1];
        f32x2 bw23;  bw23.x = s_misc[2]; bw23.y = s_misc[3];
        sfeat[grp][0][lt] = pk_fma(ssum2, bw01, a01);
        sfeat[grp][1][lt] = pk_fma(ssum2, bw23, a23);
    }

    __syncthreads();

    // ---- phase B: gather 4 window neighbors from both group partials ----
    if (tid < TW * TH) {
        const int lx = tid & (TW - 1);
        const int ly = tid >> 5;
        const int oy = ty0 + ly, ox = tx0 + lx;
        const int i00 = ly * LW + lx;
        const f32x2 g0r0 = sfeat[0][0][i00];
        const f32x2 g0r1 = sfeat[0][0][i00 + 1];
        const f32x2 g0r2 = sfeat[0][1][i00 + LW];
        const f32x2 g0r3 = sfeat[0][1][i00 + LW + 1];
        const f32x2 g1r0 = sfeat[1][0][i00];
        const f32x2 g1r1 = sfeat[1][0][i00 + 1];
        const f32x2 g1r2 = sfeat[1][1][i00 + LW];
        const f32x2 g1r3 = sfeat[1][1][i00 + LW + 1];
        const float acc = (g0r0.x + g0r1.y) + (g0r2.x + g0r3.y)
                        + (g1r0.x + g1r1.y) + (g1r2.x + g1r3.y);
        if (oy < Ho && ox < Wo)
            out[((size_t)b * Ho + oy) * Wo + ox] = acc;
    }
}

extern "C" void kernel_launch(void* const* d_in, const int* in_sizes, int n_in,
                              void* d_out, int out_size, void* d_ws, size_t ws_size,
                              hipStream_t stream) {
    const float* x        = (const float*)d_in[0];
    const float* base_w   = (const float*)d_in[1];
    const float* spline_w = (const float*)d_in[2];
    const float* spline_s = (const float*)d_in[3];
    const float* grid     = (const float*)d_in[4];
    float* out = (float*)d_out;

    const int B = 8, C = 16, H = 128, W = 128;

    // 4 xtiles x 16 ytiles x 8 batches = 512 blocks x 640 threads;
    // every output written exactly once -> no memset, no atomics.
    kan_conv_kernel<<<512, NT, 0, stream>>>(
        x, base_w, spline_w, spline_s, grid, out, B, C, H, W);
}